// Round 1
// baseline (1336.804 us; speedup 1.0000x reference)
//
#include <hip/hip_runtime.h>
#include <math.h>

#define M_PIf 3.14159265358979323846f
// log(0.01)/1.5, log(0.01)/0.3
#define MIND (-3.0701134573253936f)
#define MAXD (-15.350567286626968f)

// ---------------------------------------------------------------------------
// GEMM1: up_t[b, e, l] = sum_d u[b,l,d] * in_w[d,e] + in_b[e]
// M = 8192 (b,l), N = 3072 (e), K = 1024 (d). BM=BN=128, BK=16, 256 thr, 8x8.
// ---------------------------------------------------------------------------
__global__ __launch_bounds__(256) void gemm1_kernel(
    const float* __restrict__ U, const float* __restrict__ W,
    const float* __restrict__ bias, float* __restrict__ up_t)
{
    __shared__ float As[16][136];
    __shared__ float Bs[16][136];
    const int n0 = blockIdx.x * 128;
    const int m0 = blockIdx.y * 128;
    const int b  = m0 >> 11;
    const int l0 = m0 & 2047;
    const int tid = threadIdx.x;
    const int tx = tid & 15, ty = tid >> 4;

    float acc[8][8];
#pragma unroll
    for (int i = 0; i < 8; ++i)
#pragma unroll
        for (int j = 0; j < 8; ++j) acc[i][j] = 0.f;

    for (int k0 = 0; k0 < 1024; k0 += 16) {
        __syncthreads();
        // A tile: 128 rows(l) x 16 k, transposed store
#pragma unroll
        for (int h = 0; h < 2; ++h) {
            int f = tid + h * 256;          // float4 id 0..511
            int r = f >> 2, kq = f & 3;
            const float4 v = *(const float4*)(&U[((size_t)(b * 2048 + l0 + r)) * 1024 + k0 + kq * 4]);
            As[kq * 4 + 0][r] = v.x;
            As[kq * 4 + 1][r] = v.y;
            As[kq * 4 + 2][r] = v.z;
            As[kq * 4 + 3][r] = v.w;
        }
        // B tile: 16 k x 128 n
#pragma unroll
        for (int h = 0; h < 2; ++h) {
            int f = tid + h * 256;
            int kk = f >> 5, j4 = f & 31;
            *(float4*)(&Bs[kk][j4 * 4]) =
                *(const float4*)(&W[((size_t)(k0 + kk)) * 3072 + n0 + j4 * 4]);
        }
        __syncthreads();
#pragma unroll
        for (int kk = 0; kk < 16; ++kk) {
            float4 a0 = *(const float4*)&As[kk][ty * 8];
            float4 a1 = *(const float4*)&As[kk][ty * 8 + 4];
            float4 b0 = *(const float4*)&Bs[kk][tx * 8];
            float4 b1 = *(const float4*)&Bs[kk][tx * 8 + 4];
            float a[8] = {a0.x, a0.y, a0.z, a0.w, a1.x, a1.y, a1.z, a1.w};
            float bb[8] = {b0.x, b0.y, b0.z, b0.w, b1.x, b1.y, b1.z, b1.w};
#pragma unroll
            for (int i = 0; i < 8; ++i)
#pragma unroll
                for (int j = 0; j < 8; ++j)
                    acc[i][j] += a[i] * bb[j];
        }
    }
    // write up_t[b, e, l]; e = n0+tx*8+j, l = l0+ty*8+i
#pragma unroll
    for (int j = 0; j < 8; ++j) {
        int e = n0 + tx * 8 + j;
        float bv = bias[e];
        float* dst = &up_t[((size_t)b * 3072 + e) * 2048 + l0 + ty * 8];
        float4 o0 = make_float4(acc[0][j] + bv, acc[1][j] + bv, acc[2][j] + bv, acc[3][j] + bv);
        float4 o1 = make_float4(acc[4][j] + bv, acc[5][j] + bv, acc[6][j] + bv, acc[7][j] + bv);
        *(float4*)(dst) = o0;
        *(float4*)(dst + 4) = o1;
    }
}

// ---------------------------------------------------------------------------
// Filter MLP: k[d, l] = (h3(l) @ mlp_wo)[d] * exp(-t_l*|delta_d|)
// one block per position l
// ---------------------------------------------------------------------------
__global__ __launch_bounds__(256) void filt_kernel(
    const float* __restrict__ w1, const float* __restrict__ b1,
    const float* __restrict__ w2, const float* __restrict__ b2,
    const float* __restrict__ w3, const float* __restrict__ b3,
    const float* __restrict__ wo, const float* __restrict__ freq,
    float* __restrict__ kbuf)
{
    __shared__ float h1[64], h2[64], h3[64];
    const int l = blockIdx.x;
    const int tid = threadIdx.x;
    const float t = (float)l * (1.0f / 2047.0f);
    const float ang = 1e-4f * (2.0f * M_PIf) * ((float)l / 2048.0f);
    const float z0 = t, z1 = cosf(ang), z2 = -sinf(ang);
    if (tid < 64) {
        float pre = z0 * w1[tid] + z1 * w1[64 + tid] + z2 * w1[128 + tid] + b1[tid];
        h1[tid] = sinf(freq[tid] * pre);
    }
    __syncthreads();
    if (tid < 64) {
        float s = b2[tid];
#pragma unroll
        for (int i = 0; i < 64; ++i) s += h1[i] * w2[i * 64 + tid];
        h2[tid] = sinf(freq[tid] * s);
    }
    __syncthreads();
    if (tid < 64) {
        float s = b3[tid];
#pragma unroll
        for (int i = 0; i < 64; ++i) s += h2[i] * w3[i * 64 + tid];
        h3[tid] = sinf(freq[tid] * s);
    }
    __syncthreads();
    const float span = (MAXD - MIND) * (1.0f / 1023.0f);
#pragma unroll
    for (int q = 0; q < 4; ++q) {
        int dd = tid + 256 * q;
        float s = 0.f;
#pragma unroll
        for (int i = 0; i < 64; ++i) s += h3[i] * wo[i * 1024 + dd];
        float delta = MIND + span * (float)dd;
        kbuf[(size_t)dd * 2048 + l] = s * expf(-t * fabsf(delta));
    }
}

// ---------------------------------------------------------------------------
// Fused: depthwise conv3 -> vx = v*x1 ; y = causal_conv(vx, k) ;
//        yv = (y + vx*fb)*x0.  One block per (b,d).
// ---------------------------------------------------------------------------
__global__ __launch_bounds__(256) void conv_kernel(
    const float* __restrict__ up_t, const float* __restrict__ kbuf,
    const float* __restrict__ sw, const float* __restrict__ sb,
    const float* __restrict__ fbias, float* __restrict__ yv)
{
    __shared__ float u1s[2048], u2s[2048], vxs[2048], ks[2048];
    const int bx = blockIdx.x;
    const int b = bx >> 10, d = bx & 1023;
    const int tid = threadIdx.x;

    const float* rx1 = up_t + ((size_t)b * 3072 + 1024 + d) * 2048;
    const float* rv  = up_t + ((size_t)b * 3072 + 2048 + d) * 2048;
    const float* kr  = kbuf + (size_t)d * 2048;
#pragma unroll
    for (int h = 0; h < 2; ++h) {
        int i = tid + h * 256;
        ((float4*)u1s)[i] = ((const float4*)rx1)[i];
        ((float4*)u2s)[i] = ((const float4*)rv)[i];
        ((float4*)ks)[i]  = ((const float4*)kr)[i];
    }
    __syncthreads();
    const float w1a = sw[(1024 + d) * 3 + 0], w1b = sw[(1024 + d) * 3 + 1], w1c = sw[(1024 + d) * 3 + 2];
    const float w2a = sw[(2048 + d) * 3 + 0], w2b = sw[(2048 + d) * 3 + 1], w2c = sw[(2048 + d) * 3 + 2];
    const float sb1 = sb[1024 + d], sb2 = sb[2048 + d];
#pragma unroll
    for (int h = 0; h < 8; ++h) {
        int l = tid + h * 256;
        float a2 = (l >= 2) ? u1s[l - 2] : 0.f;
        float a1 = (l >= 1) ? u1s[l - 1] : 0.f;
        float x1v = w1a * a2 + w1b * a1 + w1c * u1s[l] + sb1;
        float c2 = (l >= 2) ? u2s[l - 2] : 0.f;
        float c1 = (l >= 1) ? u2s[l - 1] : 0.f;
        float vv = w2a * c2 + w2b * c1 + w2c * u2s[l] + sb2;
        vxs[l] = vv * x1v;
    }
    __syncthreads();
    const float* r0 = up_t + ((size_t)b * 3072 + d) * 2048;
#pragma unroll
    for (int h = 0; h < 2; ++h) {
        int i = tid + h * 256;
        ((float4*)u2s)[i] = ((const float4*)r0)[i];
    }
    __syncthreads();
    const float w0a = sw[d * 3 + 0], w0b = sw[d * 3 + 1], w0c = sw[d * 3 + 2];
    const float sb0 = sb[d];
#pragma unroll
    for (int h = 0; h < 8; ++h) {
        int l = tid + h * 256;
        float a2 = (l >= 2) ? u2s[l - 2] : 0.f;
        float a1 = (l >= 1) ? u2s[l - 1] : 0.f;
        u1s[l] = w0a * a2 + w0b * a1 + w0c * u2s[l] + sb0;   // x0 row
    }
    __syncthreads();

    const int l0 = tid * 8;
    float acc[8] = {0.f, 0.f, 0.f, 0.f, 0.f, 0.f, 0.f, 0.f};

    const int nfull = tid;   // number of full 8-m blocks
    if (nfull > 0) {
        float win[16];   // win[j] = ks[A + j], A = l0 - m0 - 8
        {
            float4 w0 = *(const float4*)&ks[l0 - 8];
            float4 w1 = *(const float4*)&ks[l0 - 4];
            float4 w2 = *(const float4*)&ks[l0];
            float4 w3 = *(const float4*)&ks[l0 + 4];
            win[0] = w0.x; win[1] = w0.y; win[2]  = w0.z; win[3]  = w0.w;
            win[4] = w1.x; win[5] = w1.y; win[6]  = w1.z; win[7]  = w1.w;
            win[8] = w2.x; win[9] = w2.y; win[10] = w2.z; win[11] = w2.w;
            win[12] = w3.x; win[13] = w3.y; win[14] = w3.z; win[15] = w3.w;
        }
        for (int blk = 0; blk < nfull; ++blk) {
            const int m0 = blk * 8;
            float4 v0 = *(const float4*)&vxs[m0];
            float4 v1 = *(const float4*)&vxs[m0 + 4];
            float vv[8] = {v0.x, v0.y, v0.z, v0.w, v1.x, v1.y, v1.z, v1.w};
#pragma unroll
            for (int mm = 0; mm < 8; ++mm)
#pragma unroll
                for (int i = 0; i < 8; ++i)
                    acc[i] += vv[mm] * win[8 + i - mm];
            if (blk + 1 < nfull) {
                const int base = l0 - m0 - 16;
                float4 nn0 = *(const float4*)&ks[base];
                float4 nn1 = *(const float4*)&ks[base + 4];
#pragma unroll
                for (int j = 0; j < 8; ++j) win[j + 8] = win[j];
                win[0] = nn0.x; win[1] = nn0.y; win[2] = nn0.z; win[3] = nn0.w;
                win[4] = nn1.x; win[5] = nn1.y; win[6] = nn1.z; win[7] = nn1.w;
            }
        }
    }
    // tail: m = l0 .. l0+7, k index = i - mm
#pragma unroll
    for (int mm = 0; mm < 8; ++mm) {
        const float vvt = vxs[l0 + mm];
#pragma unroll
        for (int i = mm; i < 8; ++i)
            acc[i] += vvt * ks[i - mm];
    }

    const float fb = fbias[d];
    float4 va = *(const float4*)&vxs[l0];
    float4 vb = *(const float4*)&vxs[l0 + 4];
    float4 xa = *(const float4*)&u1s[l0];
    float4 xb = *(const float4*)&u1s[l0 + 4];
    float vxv[8] = {va.x, va.y, va.z, va.w, vb.x, vb.y, vb.z, vb.w};
    float x0v[8] = {xa.x, xa.y, xa.z, xa.w, xb.x, xb.y, xb.z, xb.w};
    float o[8];
#pragma unroll
    for (int i = 0; i < 8; ++i) o[i] = (acc[i] + vxv[i] * fb) * x0v[i];
    float* dst = yv + ((size_t)b * 1024 + d) * 2048 + l0;
    *(float4*)dst = make_float4(o[0], o[1], o[2], o[3]);
    *(float4*)(dst + 4) = make_float4(o[4], o[5], o[6], o[7]);
}

// ---------------------------------------------------------------------------
// GEMM2: out[b, l, e] = sum_d yv[b,d,l] * out_w[d,e] + out_b[e]
// ---------------------------------------------------------------------------
__global__ __launch_bounds__(256) void gemm2_kernel(
    const float* __restrict__ yv, const float* __restrict__ W,
    const float* __restrict__ bias, float* __restrict__ out)
{
    __shared__ float As[16][136];
    __shared__ float Bs[16][136];
    const int n0 = blockIdx.x * 128;
    const int m0 = blockIdx.y * 128;
    const int b  = m0 >> 11;
    const int l0 = m0 & 2047;
    const int tid = threadIdx.x;
    const int tx = tid & 15, ty = tid >> 4;

    float acc[8][8];
#pragma unroll
    for (int i = 0; i < 8; ++i)
#pragma unroll
        for (int j = 0; j < 8; ++j) acc[i][j] = 0.f;

    for (int k0 = 0; k0 < 1024; k0 += 16) {
        __syncthreads();
        // A tile: As[kk][r] = yv[b, k0+kk, l0+r] (coalesced along l)
#pragma unroll
        for (int h = 0; h < 2; ++h) {
            int f = tid + h * 256;
            int kk = f >> 5, r4 = f & 31;
            *(float4*)(&As[kk][r4 * 4]) =
                *(const float4*)(&yv[((size_t)b * 1024 + k0 + kk) * 2048 + l0 + r4 * 4]);
        }
#pragma unroll
        for (int h = 0; h < 2; ++h) {
            int f = tid + h * 256;
            int kk = f >> 5, j4 = f & 31;
            *(float4*)(&Bs[kk][j4 * 4]) =
                *(const float4*)(&W[((size_t)(k0 + kk)) * 1024 + n0 + j4 * 4]);
        }
        __syncthreads();
#pragma unroll
        for (int kk = 0; kk < 16; ++kk) {
            float4 a0 = *(const float4*)&As[kk][ty * 8];
            float4 a1 = *(const float4*)&As[kk][ty * 8 + 4];
            float4 b0 = *(const float4*)&Bs[kk][tx * 8];
            float4 b1 = *(const float4*)&Bs[kk][tx * 8 + 4];
            float a[8] = {a0.x, a0.y, a0.z, a0.w, a1.x, a1.y, a1.z, a1.w};
            float bb[8] = {b0.x, b0.y, b0.z, b0.w, b1.x, b1.y, b1.z, b1.w};
#pragma unroll
            for (int i = 0; i < 8; ++i)
#pragma unroll
                for (int j = 0; j < 8; ++j)
                    acc[i][j] += a[i] * bb[j];
        }
    }
    float bv[8];
#pragma unroll
    for (int j = 0; j < 8; ++j) bv[j] = bias[n0 + tx * 8 + j];
#pragma unroll
    for (int i = 0; i < 8; ++i) {
        float* dst = &out[((size_t)(b * 2048 + l0 + ty * 8 + i)) * 1024 + n0 + tx * 8];
        float4 o0 = make_float4(acc[i][0] + bv[0], acc[i][1] + bv[1], acc[i][2] + bv[2], acc[i][3] + bv[3]);
        float4 o1 = make_float4(acc[i][4] + bv[4], acc[i][5] + bv[5], acc[i][6] + bv[6], acc[i][7] + bv[7]);
        *(float4*)(dst) = o0;
        *(float4*)(dst + 4) = o1;
    }
}

extern "C" void kernel_launch(void* const* d_in, const int* in_sizes, int n_in,
                              void* d_out, int out_size, void* d_ws, size_t ws_size,
                              hipStream_t stream) {
    (void)in_sizes; (void)n_in; (void)out_size; (void)ws_size;
    const float* u         = (const float*)d_in[0];
    const float* in_w      = (const float*)d_in[1];
    const float* in_b      = (const float*)d_in[2];
    const float* short_w   = (const float*)d_in[3];
    const float* short_b   = (const float*)d_in[4];
    const float* mlp_w1    = (const float*)d_in[5];
    const float* mlp_b1    = (const float*)d_in[6];
    const float* mlp_w2    = (const float*)d_in[7];
    const float* mlp_b2    = (const float*)d_in[8];
    const float* mlp_w3    = (const float*)d_in[9];
    const float* mlp_b3    = (const float*)d_in[10];
    const float* mlp_wo    = (const float*)d_in[11];
    const float* freq      = (const float*)d_in[12];
    const float* filt_bias = (const float*)d_in[13];
    const float* out_w     = (const float*)d_in[14];
    const float* out_b     = (const float*)d_in[15];
    float* out = (float*)d_out;

    char* ws = (char*)d_ws;
    float* up_t = (float*)ws;                                   // 4*3072*2048 f32 = 96 MiB
    float* kbuf = (float*)(ws + 100663296);                     // 1024*2048 f32 = 8 MiB
    float* yvb  = (float*)(ws + 100663296 + 8388608);           // 4*1024*2048 f32 = 32 MiB

    hipLaunchKernelGGL(gemm1_kernel, dim3(24, 64), dim3(256), 0, stream, u, in_w, in_b, up_t);
    hipLaunchKernelGGL(filt_kernel, dim3(2048), dim3(256), 0, stream,
                       mlp_w1, mlp_b1, mlp_w2, mlp_b2, mlp_w3, mlp_b3, mlp_wo, freq, kbuf);
    hipLaunchKernelGGL(conv_kernel, dim3(4096), dim3(256), 0, stream,
                       up_t, kbuf, short_w, short_b, filt_bias, yvb);
    hipLaunchKernelGGL(gemm2_kernel, dim3(8, 64), dim3(256), 0, stream, yvb, out_w, out_b, out);
}

// Round 2
// 735.964 us; speedup vs baseline: 1.8164x; 1.8164x over previous
//
#include <hip/hip_runtime.h>
#include <math.h>

#define M_PIf 3.14159265358979323846f
#define MIND (-3.0701134573253936f)
#define MAXD (-15.350567286626968f)

typedef __attribute__((ext_vector_type(8))) short bf16x8;
typedef __attribute__((ext_vector_type(4))) float f32x4;

#define GLDS(g, l) __builtin_amdgcn_global_load_lds(                         \
    (const __attribute__((address_space(1))) void*)(g),                      \
    (__attribute__((address_space(3))) void*)(l), 16, 0, 0)

__device__ __forceinline__ unsigned short f2bf(float x) {
    unsigned u = __builtin_bit_cast(unsigned, x);
    u = (u + 0x7fff + ((u >> 16) & 1)) >> 16;
    return (unsigned short)u;
}
__device__ __forceinline__ float bf2f(unsigned short h) {
    unsigned u = ((unsigned)h) << 16;
    return __builtin_bit_cast(float, u);
}

// ---------------------------------------------------------------------------
// split: f32 array -> hi/lo bf16 arrays (same layout)
// ---------------------------------------------------------------------------
__global__ __launch_bounds__(256) void split_kernel(
    const float* __restrict__ in, unsigned short* __restrict__ hi,
    unsigned short* __restrict__ lo, int n4)
{
    int i = blockIdx.x * 256 + threadIdx.x;
    if (i >= n4) return;
    float4 v = ((const float4*)in)[i];
    ushort4 h, l;
    h.x = f2bf(v.x); l.x = f2bf(v.x - bf2f(h.x));
    h.y = f2bf(v.y); l.y = f2bf(v.y - bf2f(h.y));
    h.z = f2bf(v.z); l.z = f2bf(v.z - bf2f(h.z));
    h.w = f2bf(v.w); l.w = f2bf(v.w - bf2f(h.w));
    ((ushort4*)hi)[i] = h;
    ((ushort4*)lo)[i] = l;
}

// ---------------------------------------------------------------------------
// transpose + split: in[R][C] f32 -> hi/lo[C][R] bf16 (batched via z)
// ---------------------------------------------------------------------------
__global__ __launch_bounds__(256) void tsplit_kernel(
    const float* __restrict__ in, unsigned short* __restrict__ hi,
    unsigned short* __restrict__ lo, int R, int C,
    long in_zstride, long out_zstride)
{
    __shared__ float t[32][33];
    const float* inz = in + (size_t)blockIdx.z * in_zstride;
    const int r0 = blockIdx.y * 32, c0 = blockIdx.x * 32;
    const int tx = threadIdx.x & 31, ty = threadIdx.x >> 5;
#pragma unroll
    for (int q = 0; q < 4; ++q) {
        int r = ty + q * 8;
        t[r][tx] = inz[(size_t)(r0 + r) * C + c0 + tx];
    }
    __syncthreads();
#pragma unroll
    for (int q = 0; q < 4; ++q) {
        int cc = ty + q * 8;
        float v = t[tx][cc];
        unsigned short h = f2bf(v);
        unsigned short l = f2bf(v - bf2f(h));
        size_t o = (size_t)blockIdx.z * out_zstride + (size_t)(c0 + cc) * R + r0 + tx;
        hi[o] = h;
        lo[o] = l;
    }
}

// ---------------------------------------------------------------------------
// Split-bf16 MFMA GEMM: C[M x N] = A[M x 1024] @ B[1024 x N] (+bias on N)
// A given as Ahi/Alo row-major [M][1024]; B given TRANSPOSED as Bhi/Blo [N][1024].
// 128x128 tile, BK=32, 256 thr (4 waves, each 64x64), 16x16x32 bf16 MFMA x3.
// TRANS_OUT=1: out[b][e=n][l] (up_t layout, M=(b,l), stride 3072*2048)
// TRANS_OUT=0: out[m][n] row-major, N=1024
// ---------------------------------------------------------------------------
template <int TRANS_OUT>
__global__ __launch_bounds__(256, 2) void gemm_split_kernel(
    const unsigned short* __restrict__ Ahi, const unsigned short* __restrict__ Alo,
    const unsigned short* __restrict__ Bhi, const unsigned short* __restrict__ Blo,
    const float* __restrict__ bias, float* __restrict__ outp)
{
    __shared__ char smem[65536];   // [2 buf][4 arr][128 rows][64 B]
    const int tid = threadIdx.x;
    const int wave = tid >> 6, lane = tid & 63;
    const int n0 = blockIdx.x * 128, m0 = blockIdx.y * 128;
    const int wm = wave >> 1, wn = wave & 1;

    f32x4 acc[4][4] = {};

    const int srow = lane >> 2;          // 0..15 row within 16-row chunk
    const int scol = (lane & 3) * 16;    // byte within 64B row

    auto stage = [&](int buf, int t) {
        const int k0 = t * 32;
        char* base = smem + buf * 32768;
#pragma unroll
        for (int ld = 0; ld < 2; ++ld) {
            const int rchunk = wave * 32 + ld * 16;
            const int r = rchunk + srow;
            GLDS((const char*)(Ahi + (size_t)(m0 + r) * 1024 + k0) + scol,
                 base + 0 * 8192 + rchunk * 64);
            GLDS((const char*)(Alo + (size_t)(m0 + r) * 1024 + k0) + scol,
                 base + 1 * 8192 + rchunk * 64);
            GLDS((const char*)(Bhi + (size_t)(n0 + r) * 1024 + k0) + scol,
                 base + 2 * 8192 + rchunk * 64);
            GLDS((const char*)(Blo + (size_t)(n0 + r) * 1024 + k0) + scol,
                 base + 3 * 8192 + rchunk * 64);
        }
    };

    stage(0, 0);
    asm volatile("s_waitcnt vmcnt(0)");
    __syncthreads();
    int cur = 0;
    const int rr = lane & 15, gg = (lane >> 4) * 16;
    for (int t = 0; t < 32; ++t) {
        if (t < 31) stage(cur ^ 1, t + 1);
        const char* b = smem + cur * 32768;
        bf16x8 ah[4], al[4], bh[4], bl[4];
#pragma unroll
        for (int i = 0; i < 4; ++i) {
            ah[i] = *(const bf16x8*)(b + 0 * 8192 + (wm * 64 + i * 16 + rr) * 64 + gg);
            al[i] = *(const bf16x8*)(b + 1 * 8192 + (wm * 64 + i * 16 + rr) * 64 + gg);
            bh[i] = *(const bf16x8*)(b + 2 * 8192 + (wn * 64 + i * 16 + rr) * 64 + gg);
            bl[i] = *(const bf16x8*)(b + 3 * 8192 + (wn * 64 + i * 16 + rr) * 64 + gg);
        }
#pragma unroll
        for (int i = 0; i < 4; ++i)
#pragma unroll
            for (int j = 0; j < 4; ++j) {
                acc[i][j] = __builtin_amdgcn_mfma_f32_16x16x32_bf16(ah[i], bh[j], acc[i][j], 0, 0, 0);
                acc[i][j] = __builtin_amdgcn_mfma_f32_16x16x32_bf16(ah[i], bl[j], acc[i][j], 0, 0, 0);
                acc[i][j] = __builtin_amdgcn_mfma_f32_16x16x32_bf16(al[i], bh[j], acc[i][j], 0, 0, 0);
            }
        __syncthreads();
        cur ^= 1;
    }

    const int c = lane & 15, g4 = lane >> 4;
    if (TRANS_OUT) {
        // transpose 64x64 wave tile through LDS, write up_t[b][e][l] coalesced
        float* scr = (float*)smem + wave * (32 * 68);
        const int bidx = m0 >> 11;
        const int lbase = (m0 & 2047) + wm * 64;
#pragma unroll
        for (int p = 0; p < 2; ++p) {
#pragma unroll
            for (int j = 0; j < 2; ++j) {
                const int jj = p * 2 + j;
                const float bv = bias[n0 + wn * 64 + jj * 16 + c];
#pragma unroll
                for (int i = 0; i < 4; ++i)
#pragma unroll
                    for (int r = 0; r < 4; ++r)
                        scr[(j * 16 + c) * 68 + i * 16 + g4 * 4 + r] = acc[i][jj][r] + bv;
            }
#pragma unroll
            for (int it = 0; it < 8; ++it) {
                const int row = it * 4 + g4;    // 0..31 (n_local in pass)
                float4 v = *(const float4*)&scr[row * 68 + c * 4];
                const int e = n0 + wn * 64 + p * 32 + row;
                *(float4*)&outp[((size_t)bidx * 3072 + e) * 2048 + lbase + c * 4] = v;
            }
            __syncthreads();
        }
    } else {
#pragma unroll
        for (int j = 0; j < 4; ++j) {
            const int col = n0 + wn * 64 + j * 16 + c;
            const float bv = bias[col];
#pragma unroll
            for (int i = 0; i < 4; ++i) {
                const int row = m0 + wm * 64 + i * 16 + g4 * 4;
#pragma unroll
                for (int r = 0; r < 4; ++r)
                    outp[(size_t)(row + r) * 1024 + col] = acc[i][j][r] + bv;
            }
        }
    }
}

// ---------------------------------------------------------------------------
// Filter MLP: k[d, l]
// ---------------------------------------------------------------------------
__global__ __launch_bounds__(256) void filt_kernel(
    const float* __restrict__ w1, const float* __restrict__ b1,
    const float* __restrict__ w2, const float* __restrict__ b2,
    const float* __restrict__ w3, const float* __restrict__ b3,
    const float* __restrict__ wo, const float* __restrict__ freq,
    float* __restrict__ kbuf)
{
    __shared__ float h1[64], h2[64], h3[64];
    const int l = blockIdx.x;
    const int tid = threadIdx.x;
    const float t = (float)l * (1.0f / 2047.0f);
    const float ang = 1e-4f * (2.0f * M_PIf) * ((float)l / 2048.0f);
    const float z0 = t, z1 = cosf(ang), z2 = -sinf(ang);
    if (tid < 64) {
        float pre = z0 * w1[tid] + z1 * w1[64 + tid] + z2 * w1[128 + tid] + b1[tid];
        h1[tid] = sinf(freq[tid] * pre);
    }
    __syncthreads();
    if (tid < 64) {
        float s = b2[tid];
#pragma unroll
        for (int i = 0; i < 64; ++i) s += h1[i] * w2[i * 64 + tid];
        h2[tid] = sinf(freq[tid] * s);
    }
    __syncthreads();
    if (tid < 64) {
        float s = b3[tid];
#pragma unroll
        for (int i = 0; i < 64; ++i) s += h2[i] * w3[i * 64 + tid];
        h3[tid] = sinf(freq[tid] * s);
    }
    __syncthreads();
    const float span = (MAXD - MIND) * (1.0f / 1023.0f);
#pragma unroll
    for (int q = 0; q < 4; ++q) {
        int dd = tid + 256 * q;
        float s = 0.f;
#pragma unroll
        for (int i = 0; i < 64; ++i) s += h3[i] * wo[i * 1024 + dd];
        float delta = MIND + span * (float)dd;
        kbuf[(size_t)dd * 2048 + l] = s * expf(-t * fabsf(delta));
    }
}

// ---------------------------------------------------------------------------
// Fused depthwise conv3 + gating + O(L^2) causal conv + output gate.
// LDS XOR swizzle: 16B-block q -> q ^ ((q>>3)&1) spreads the all-even-block
// window reads over all 32 banks.
// ---------------------------------------------------------------------------
__device__ __forceinline__ int SWW(int w) { return w ^ (((w >> 5) & 1) << 2); }
__device__ __forceinline__ int SWQ(int q) { return q ^ ((q >> 3) & 1); }

__global__ __launch_bounds__(256) void conv_kernel(
    const float* __restrict__ up_t, const float* __restrict__ kbuf,
    const float* __restrict__ sw, const float* __restrict__ sb,
    const float* __restrict__ fbias, float* __restrict__ yv)
{
    __shared__ float u1s[2048], u2s[2048], vxs[2048], ks[2048];
    const int bx = blockIdx.x;
    const int b = bx >> 10, d = bx & 1023;
    const int tid = threadIdx.x;

    const float* rx1 = up_t + ((size_t)b * 3072 + 1024 + d) * 2048;
    const float* rv  = up_t + ((size_t)b * 3072 + 2048 + d) * 2048;
    const float* kr  = kbuf + (size_t)d * 2048;
#pragma unroll
    for (int h = 0; h < 2; ++h) {
        int i = tid + h * 256;
        ((float4*)u1s)[SWQ(i)] = ((const float4*)rx1)[i];
        ((float4*)u2s)[SWQ(i)] = ((const float4*)rv)[i];
        ((float4*)ks)[SWQ(i)]  = ((const float4*)kr)[i];
    }
    __syncthreads();
    const float w1a = sw[(1024 + d) * 3 + 0], w1b = sw[(1024 + d) * 3 + 1], w1c = sw[(1024 + d) * 3 + 2];
    const float w2a = sw[(2048 + d) * 3 + 0], w2b = sw[(2048 + d) * 3 + 1], w2c = sw[(2048 + d) * 3 + 2];
    const float sb1 = sb[1024 + d], sb2 = sb[2048 + d];
#pragma unroll
    for (int h = 0; h < 8; ++h) {
        int l = tid + h * 256;
        float a2 = (l >= 2) ? u1s[SWW(l - 2)] : 0.f;
        float a1 = (l >= 1) ? u1s[SWW(l - 1)] : 0.f;
        float x1v = w1a * a2 + w1b * a1 + w1c * u1s[SWW(l)] + sb1;
        float c2 = (l >= 2) ? u2s[SWW(l - 2)] : 0.f;
        float c1 = (l >= 1) ? u2s[SWW(l - 1)] : 0.f;
        float vv = w2a * c2 + w2b * c1 + w2c * u2s[SWW(l)] + sb2;
        vxs[SWW(l)] = vv * x1v;
    }
    __syncthreads();
    const float* r0 = up_t + ((size_t)b * 3072 + d) * 2048;
#pragma unroll
    for (int h = 0; h < 2; ++h) {
        int i = tid + h * 256;
        ((float4*)u2s)[SWQ(i)] = ((const float4*)r0)[i];
    }
    __syncthreads();
    const float w0a = sw[d * 3 + 0], w0b = sw[d * 3 + 1], w0c = sw[d * 3 + 2];
    const float sb0 = sb[d];
#pragma unroll
    for (int h = 0; h < 8; ++h) {
        int l = tid + h * 256;
        float a2 = (l >= 2) ? u2s[SWW(l - 2)] : 0.f;
        float a1 = (l >= 1) ? u2s[SWW(l - 1)] : 0.f;
        u1s[SWW(l)] = w0a * a2 + w0b * a1 + w0c * u2s[SWW(l)] + sb0;   // x0 row
    }
    __syncthreads();

    const int l0 = tid * 8;
    float acc[8] = {0.f, 0.f, 0.f, 0.f, 0.f, 0.f, 0.f, 0.f};

    const int nfull = tid;
    if (nfull > 0) {
        float win[16];   // win[j] = ks[l0 - m0 - 8 + j]
        {
            float4 w0 = ((const float4*)ks)[SWQ(2 * tid - 2)];
            float4 w1 = ((const float4*)ks)[SWQ(2 * tid - 1)];
            float4 w2 = ((const float4*)ks)[SWQ(2 * tid)];
            float4 w3 = ((const float4*)ks)[SWQ(2 * tid + 1)];
            win[0] = w0.x; win[1] = w0.y; win[2]  = w0.z; win[3]  = w0.w;
            win[4] = w1.x; win[5] = w1.y; win[6]  = w1.z; win[7]  = w1.w;
            win[8] = w2.x; win[9] = w2.y; win[10] = w2.z; win[11] = w2.w;
            win[12] = w3.x; win[13] = w3.y; win[14] = w3.z; win[15] = w3.w;
        }
        for (int blk = 0; blk < nfull; ++blk) {
            float4 v0 = ((const float4*)vxs)[SWQ(2 * blk)];
            float4 v1 = ((const float4*)vxs)[SWQ(2 * blk + 1)];
            float vv[8] = {v0.x, v0.y, v0.z, v0.w, v1.x, v1.y, v1.z, v1.w};
#pragma unroll
            for (int mm = 0; mm < 8; ++mm)
#pragma unroll
                for (int i = 0; i < 8; ++i)
                    acc[i] += vv[mm] * win[8 + i - mm];
            if (blk + 1 < nfull) {
                float4 nn0 = ((const float4*)ks)[SWQ(2 * (tid - blk - 2))];
                float4 nn1 = ((const float4*)ks)[SWQ(2 * (tid - blk - 2) + 1)];
#pragma unroll
                for (int j = 0; j < 8; ++j) win[j + 8] = win[j];
                win[0] = nn0.x; win[1] = nn0.y; win[2] = nn0.z; win[3] = nn0.w;
                win[4] = nn1.x; win[5] = nn1.y; win[6] = nn1.z; win[7] = nn1.w;
            }
        }
    }
#pragma unroll
    for (int mm = 0; mm < 8; ++mm) {
        const float vvt = vxs[SWW(l0 + mm)];
#pragma unroll
        for (int i = mm; i < 8; ++i)
            acc[i] += vvt * ks[SWW(i - mm)];
    }

    const float fb = fbias[d];
    float4 va = ((const float4*)vxs)[SWQ(2 * tid)];
    float4 vb = ((const float4*)vxs)[SWQ(2 * tid + 1)];
    float4 xa = ((const float4*)u1s)[SWQ(2 * tid)];
    float4 xb = ((const float4*)u1s)[SWQ(2 * tid + 1)];
    float vxv[8] = {va.x, va.y, va.z, va.w, vb.x, vb.y, vb.z, vb.w};
    float x0v[8] = {xa.x, xa.y, xa.z, xa.w, xb.x, xb.y, xb.z, xb.w};
    float o[8];
#pragma unroll
    for (int i = 0; i < 8; ++i) o[i] = (acc[i] + vxv[i] * fb) * x0v[i];
    float* dst = yv + ((size_t)b * 1024 + d) * 2048 + l0;
    *(float4*)dst = make_float4(o[0], o[1], o[2], o[3]);
    *(float4*)(dst + 4) = make_float4(o[4], o[5], o[6], o[7]);
}

extern "C" void kernel_launch(void* const* d_in, const int* in_sizes, int n_in,
                              void* d_out, int out_size, void* d_ws, size_t ws_size,
                              hipStream_t stream) {
    (void)in_sizes; (void)n_in; (void)out_size; (void)ws_size;
    const float* u         = (const float*)d_in[0];
    const float* in_w      = (const float*)d_in[1];
    const float* in_b      = (const float*)d_in[2];
    const float* short_w   = (const float*)d_in[3];
    const float* short_b   = (const float*)d_in[4];
    const float* mlp_w1    = (const float*)d_in[5];
    const float* mlp_b1    = (const float*)d_in[6];
    const float* mlp_w2    = (const float*)d_in[7];
    const float* mlp_b2    = (const float*)d_in[8];
    const float* mlp_w3    = (const float*)d_in[9];
    const float* mlp_b3    = (const float*)d_in[10];
    const float* mlp_wo    = (const float*)d_in[11];
    const float* freq      = (const float*)d_in[12];
    const float* filt_bias = (const float*)d_in[13];
    const float* out_w     = (const float*)d_in[14];
    const float* out_b     = (const float*)d_in[15];
    float* out = (float*)d_out;

    char* ws = (char*)d_ws;
    const size_t MB = 1024 * 1024;
    float*          up_t    = (float*)ws;                       // [0,96M)
    unsigned short* yvt_hi  = (unsigned short*)ws;              // reuse after conv [0,16M)
    unsigned short* yvt_lo  = (unsigned short*)(ws + 16 * MB);  // [16,32M)
    float*          kbuf    = (float*)(ws + 96 * MB);           // [96,104M)
    unsigned short* uhi     = (unsigned short*)(ws + 104 * MB); // [104,120M)
    unsigned short* ulo     = (unsigned short*)(ws + 120 * MB); // [120,136M)
    float*          yvb     = (float*)(ws + 104 * MB);          // reuse after gemm1 [104,136M)
    unsigned short* w1t_hi  = (unsigned short*)(ws + 136 * MB); // [136,142M)
    unsigned short* w1t_lo  = (unsigned short*)(ws + 142 * MB); // [142,148M)
    unsigned short* w2t_hi  = (unsigned short*)(ws + 148 * MB); // [148,150M)
    unsigned short* w2t_lo  = (unsigned short*)(ws + 150 * MB); // [150,152M)

    // input splits
    hipLaunchKernelGGL(split_kernel, dim3(8192), dim3(256), 0, stream,
                       u, uhi, ulo, 8192 * 1024 / 4);
    hipLaunchKernelGGL(tsplit_kernel, dim3(96, 32, 1), dim3(256), 0, stream,
                       in_w, w1t_hi, w1t_lo, 1024, 3072, 0L, 0L);
    hipLaunchKernelGGL(filt_kernel, dim3(2048), dim3(256), 0, stream,
                       mlp_w1, mlp_b1, mlp_w2, mlp_b2, mlp_w3, mlp_b3, mlp_wo, freq, kbuf);
    // GEMM1 -> up_t[b][e][l]
    hipLaunchKernelGGL((gemm_split_kernel<1>), dim3(24, 64), dim3(256), 0, stream,
                       uhi, ulo, w1t_hi, w1t_lo, in_b, up_t);
    // conv -> yv[b][d][l] (overwrites uhi/ulo region — gemm1 already done)
    hipLaunchKernelGGL(conv_kernel, dim3(4096), dim3(256), 0, stream,
                       up_t, kbuf, short_w, short_b, filt_bias, yvb);
    // transpose+split yv -> yvt[b][l][d] (overwrites up_t region — conv done)
    hipLaunchKernelGGL(tsplit_kernel, dim3(64, 32, 4), dim3(256), 0, stream,
                       yvb, yvt_hi, yvt_lo, 1024, 2048, 1024L * 2048L, 2048L * 1024L);
    hipLaunchKernelGGL(tsplit_kernel, dim3(32, 32, 1), dim3(256), 0, stream,
                       out_w, w2t_hi, w2t_lo, 1024, 1024, 0L, 0L);
    // GEMM2 -> out[b*l][e]
    hipLaunchKernelGGL((gemm_split_kernel<0>), dim3(8, 64), dim3(256), 0, stream,
                       yvt_hi, yvt_lo, w2t_hi, w2t_lo, out_b, out);
}

// Round 3
// 377.067 us; speedup vs baseline: 3.5453x; 1.9518x over previous
//
#include <hip/hip_runtime.h>
#include <math.h>

#define M_PIf 3.14159265358979323846f
#define MIND (-3.0701134573253936f)
#define MAXD (-15.350567286626968f)

typedef __attribute__((ext_vector_type(8))) short bf16x8;
typedef __attribute__((ext_vector_type(4))) float f32x4;

#define GLDS(g, l) __builtin_amdgcn_global_load_lds(                         \
    (const __attribute__((address_space(1))) void*)(g),                      \
    (__attribute__((address_space(3))) void*)(l), 16, 0, 0)

__device__ __forceinline__ unsigned short f2bf(float x) {
    unsigned u = __builtin_bit_cast(unsigned, x);
    u = (u + 0x7fff + ((u >> 16) & 1)) >> 16;
    return (unsigned short)u;
}
__device__ __forceinline__ float bf2f(unsigned short h) {
    unsigned u = ((unsigned)h) << 16;
    return __builtin_bit_cast(float, u);
}

// ---------------------------------------------------------------------------
// split: f32 array -> hi/lo bf16 arrays (same layout)
// ---------------------------------------------------------------------------
__global__ __launch_bounds__(256) void split_kernel(
    const float* __restrict__ in, unsigned short* __restrict__ hi,
    unsigned short* __restrict__ lo, int n4)
{
    int i = blockIdx.x * 256 + threadIdx.x;
    if (i >= n4) return;
    float4 v = ((const float4*)in)[i];
    ushort4 h, l;
    h.x = f2bf(v.x); l.x = f2bf(v.x - bf2f(h.x));
    h.y = f2bf(v.y); l.y = f2bf(v.y - bf2f(h.y));
    h.z = f2bf(v.z); l.z = f2bf(v.z - bf2f(h.z));
    h.w = f2bf(v.w); l.w = f2bf(v.w - bf2f(h.w));
    ((ushort4*)hi)[i] = h;
    ((ushort4*)lo)[i] = l;
}

// ---------------------------------------------------------------------------
// transpose + split: in[R][C] f32 -> hi/lo[C][R] bf16 (batched via z)
// ---------------------------------------------------------------------------
__global__ __launch_bounds__(256) void tsplit_kernel(
    const float* __restrict__ in, unsigned short* __restrict__ hi,
    unsigned short* __restrict__ lo, int R, int C,
    long in_zstride, long out_zstride)
{
    __shared__ float t[32][33];
    const float* inz = in + (size_t)blockIdx.z * in_zstride;
    const int r0 = blockIdx.y * 32, c0 = blockIdx.x * 32;
    const int tx = threadIdx.x & 31, ty = threadIdx.x >> 5;
#pragma unroll
    for (int q = 0; q < 4; ++q) {
        int r = ty + q * 8;
        t[r][tx] = inz[(size_t)(r0 + r) * C + c0 + tx];
    }
    __syncthreads();
#pragma unroll
    for (int q = 0; q < 4; ++q) {
        int cc = ty + q * 8;
        float v = t[tx][cc];
        unsigned short h = f2bf(v);
        unsigned short l = f2bf(v - bf2f(h));
        size_t o = (size_t)blockIdx.z * out_zstride + (size_t)(c0 + cc) * R + r0 + tx;
        hi[o] = h;
        lo[o] = l;
    }
}

// ---------------------------------------------------------------------------
// Split-bf16 MFMA GEMM (same as round 2): 128x128 tile, BK=32, 4 waves.
// ---------------------------------------------------------------------------
template <int TRANS_OUT>
__global__ __launch_bounds__(256, 2) void gemm_split_kernel(
    const unsigned short* __restrict__ Ahi, const unsigned short* __restrict__ Alo,
    const unsigned short* __restrict__ Bhi, const unsigned short* __restrict__ Blo,
    const float* __restrict__ bias, float* __restrict__ outp)
{
    __shared__ char smem[65536];
    const int tid = threadIdx.x;
    const int wave = tid >> 6, lane = tid & 63;
    const int n0 = blockIdx.x * 128, m0 = blockIdx.y * 128;
    const int wm = wave >> 1, wn = wave & 1;

    f32x4 acc[4][4] = {};

    const int srow = lane >> 2;
    const int scol = (lane & 3) * 16;

    auto stage = [&](int buf, int t) {
        const int k0 = t * 32;
        char* base = smem + buf * 32768;
#pragma unroll
        for (int ld = 0; ld < 2; ++ld) {
            const int rchunk = wave * 32 + ld * 16;
            const int r = rchunk + srow;
            GLDS((const char*)(Ahi + (size_t)(m0 + r) * 1024 + k0) + scol,
                 base + 0 * 8192 + rchunk * 64);
            GLDS((const char*)(Alo + (size_t)(m0 + r) * 1024 + k0) + scol,
                 base + 1 * 8192 + rchunk * 64);
            GLDS((const char*)(Bhi + (size_t)(n0 + r) * 1024 + k0) + scol,
                 base + 2 * 8192 + rchunk * 64);
            GLDS((const char*)(Blo + (size_t)(n0 + r) * 1024 + k0) + scol,
                 base + 3 * 8192 + rchunk * 64);
        }
    };

    stage(0, 0);
    asm volatile("s_waitcnt vmcnt(0)");
    __syncthreads();
    int cur = 0;
    const int rr = lane & 15, gg = (lane >> 4) * 16;
    for (int t = 0; t < 32; ++t) {
        if (t < 31) stage(cur ^ 1, t + 1);
        const char* b = smem + cur * 32768;
        bf16x8 ah[4], al[4], bh[4], bl[4];
#pragma unroll
        for (int i = 0; i < 4; ++i) {
            ah[i] = *(const bf16x8*)(b + 0 * 8192 + (wm * 64 + i * 16 + rr) * 64 + gg);
            al[i] = *(const bf16x8*)(b + 1 * 8192 + (wm * 64 + i * 16 + rr) * 64 + gg);
            bh[i] = *(const bf16x8*)(b + 2 * 8192 + (wn * 64 + i * 16 + rr) * 64 + gg);
            bl[i] = *(const bf16x8*)(b + 3 * 8192 + (wn * 64 + i * 16 + rr) * 64 + gg);
        }
#pragma unroll
        for (int i = 0; i < 4; ++i)
#pragma unroll
            for (int j = 0; j < 4; ++j) {
                acc[i][j] = __builtin_amdgcn_mfma_f32_16x16x32_bf16(ah[i], bh[j], acc[i][j], 0, 0, 0);
                acc[i][j] = __builtin_amdgcn_mfma_f32_16x16x32_bf16(ah[i], bl[j], acc[i][j], 0, 0, 0);
                acc[i][j] = __builtin_amdgcn_mfma_f32_16x16x32_bf16(al[i], bh[j], acc[i][j], 0, 0, 0);
            }
        __syncthreads();
        cur ^= 1;
    }

    const int c = lane & 15, g4 = lane >> 4;
    if (TRANS_OUT) {
        float* scr = (float*)smem + wave * (32 * 68);
        const int bidx = m0 >> 11;
        const int lbase = (m0 & 2047) + wm * 64;
#pragma unroll
        for (int p = 0; p < 2; ++p) {
#pragma unroll
            for (int j = 0; j < 2; ++j) {
                const int jj = p * 2 + j;
                const float bv = bias[n0 + wn * 64 + jj * 16 + c];
#pragma unroll
                for (int i = 0; i < 4; ++i)
#pragma unroll
                    for (int r = 0; r < 4; ++r)
                        scr[(j * 16 + c) * 68 + i * 16 + g4 * 4 + r] = acc[i][jj][r] + bv;
            }
#pragma unroll
            for (int it = 0; it < 8; ++it) {
                const int row = it * 4 + g4;
                float4 v = *(const float4*)&scr[row * 68 + c * 4];
                const int e = n0 + wn * 64 + p * 32 + row;
                *(float4*)&outp[((size_t)bidx * 3072 + e) * 2048 + lbase + c * 4] = v;
            }
            __syncthreads();
        }
    } else {
#pragma unroll
        for (int j = 0; j < 4; ++j) {
            const int col = n0 + wn * 64 + j * 16 + c;
            const float bv = bias[col];
#pragma unroll
            for (int i = 0; i < 4; ++i) {
                const int row = m0 + wm * 64 + i * 16 + g4 * 4;
#pragma unroll
                for (int r = 0; r < 4; ++r)
                    outp[(size_t)(row + r) * 1024 + col] = acc[i][j][r] + bv;
            }
        }
    }
}

// ---------------------------------------------------------------------------
// Filter MLP: k[d, l]
// ---------------------------------------------------------------------------
__global__ __launch_bounds__(256) void filt_kernel(
    const float* __restrict__ w1, const float* __restrict__ b1,
    const float* __restrict__ w2, const float* __restrict__ b2,
    const float* __restrict__ w3, const float* __restrict__ b3,
    const float* __restrict__ wo, const float* __restrict__ freq,
    float* __restrict__ kbuf)
{
    __shared__ float h1[64], h2[64], h3[64];
    const int l = blockIdx.x;
    const int tid = threadIdx.x;
    const float t = (float)l * (1.0f / 2047.0f);
    const float ang = 1e-4f * (2.0f * M_PIf) * ((float)l / 2048.0f);
    const float z0 = t, z1 = cosf(ang), z2 = -sinf(ang);
    if (tid < 64) {
        float pre = z0 * w1[tid] + z1 * w1[64 + tid] + z2 * w1[128 + tid] + b1[tid];
        h1[tid] = sinf(freq[tid] * pre);
    }
    __syncthreads();
    if (tid < 64) {
        float s = b2[tid];
#pragma unroll
        for (int i = 0; i < 64; ++i) s += h1[i] * w2[i * 64 + tid];
        h2[tid] = sinf(freq[tid] * s);
    }
    __syncthreads();
    if (tid < 64) {
        float s = b3[tid];
#pragma unroll
        for (int i = 0; i < 64; ++i) s += h2[i] * w3[i * 64 + tid];
        h3[tid] = sinf(freq[tid] * s);
    }
    __syncthreads();
    const float span = (MAXD - MIND) * (1.0f / 1023.0f);
#pragma unroll
    for (int q = 0; q < 4; ++q) {
        int dd = tid + 256 * q;
        float s = 0.f;
#pragma unroll
        for (int i = 0; i < 64; ++i) s += h3[i] * wo[i * 1024 + dd];
        float delta = MIND + span * (float)dd;
        kbuf[(size_t)dd * 2048 + l] = s * expf(-t * fabsf(delta));
    }
}

// ---------------------------------------------------------------------------
// MFMA Toeplitz causal conv, fused with depthwise conv3 gating.
// One block per d (1024 blocks), 4 waves, processes all 4 batches.
//
// y[l] = sum_r kk[r] * vx[l-r],  l = 256g + 16n + i  (g=0..7, n,i in [0,16))
// MFMA: A[i,j] = kk[r0+i-j], B[j,n] = vx[256g+16n-r0+j], r0 = 32t+16.
// A from reversed k pair-dword array (any alignment via 2-dword strided reads);
// B from front-padded (P=240) vx bf16 arrays, aligned ds_read_b128.
// Split-bf16 (hi/lo) x 3 MFMA for f32-class precision.
// ---------------------------------------------------------------------------
__global__ __launch_bounds__(256, 2) void conv_kernel(
    const float* __restrict__ up_t, const float* __restrict__ kbuf,
    const float* __restrict__ sw, const float* __restrict__ sb,
    const float* __restrict__ fbias, float* __restrict__ yv)
{
    __shared__ char smem[54272];
    // vxa: per b: hi[2304] @ b*9216, lo[2304] @ b*9216+4608   (36864 B)
    // whi[2064] int @ 36864, wlo[2064] int @ 45120            (phase 0-1)
    // x0p[2][2176] f32 @ 36864                                (phase 2, union)
#define VH(b) ((unsigned short*)(smem + (b) * 9216))
#define VL(b) ((unsigned short*)(smem + (b) * 9216 + 4608))
    int* whi = (int*)(smem + 36864);
    int* wlo = (int*)(smem + 45120);
    float* x0p = (float*)(smem + 36864);

    const int d = blockIdx.x;
    const int tid = threadIdx.x;

    // ---- phase 0a: reversed-k pair-dword arrays -----------------------------
    const float* kr = kbuf + (size_t)d * 2048;
    for (int x = tid; x < 2064; x += 256) {
        int k1 = 2047 - x;
        float f1 = (k1 >= 0) ? kr[k1] : 0.f;
        float f2 = (k1 >= 1) ? kr[k1 - 1] : 0.f;
        unsigned h1 = f2bf(f1), h2 = f2bf(f2);
        unsigned l1 = f2bf(f1 - bf2f((unsigned short)h1));
        unsigned l2 = f2bf(f2 - bf2f((unsigned short)h2));
        whi[x] = (int)(h1 | (h2 << 16));
        wlo[x] = (int)(l1 | (l2 << 16));
    }
    // ---- phase 0b: vx = conv3(x1)*conv3(v), split hi/lo, pad P=240 ----------
    const float w1a = sw[(1024 + d) * 3 + 0], w1b = sw[(1024 + d) * 3 + 1], w1c = sw[(1024 + d) * 3 + 2];
    const float w2a = sw[(2048 + d) * 3 + 0], w2b = sw[(2048 + d) * 3 + 1], w2c = sw[(2048 + d) * 3 + 2];
    const float sb1 = sb[1024 + d], sb2 = sb[2048 + d];
    for (int idx = tid; idx < 2304; idx += 256) {
        int l = idx - 240;
#pragma unroll
        for (int b = 0; b < 4; ++b) {
            float vx = 0.f;
            if (l >= 0 && l < 2048) {
                const float* rx1 = up_t + ((size_t)(b * 3072) + 1024 + d) * 2048;
                const float* rv  = up_t + ((size_t)(b * 3072) + 2048 + d) * 2048;
                float a2 = (l >= 2) ? rx1[l - 2] : 0.f;
                float a1 = (l >= 1) ? rx1[l - 1] : 0.f;
                float x1 = w1a * a2 + w1b * a1 + w1c * rx1[l] + sb1;
                float c2 = (l >= 2) ? rv[l - 2] : 0.f;
                float c1 = (l >= 1) ? rv[l - 1] : 0.f;
                float vv = w2a * c2 + w2b * c1 + w2c * rv[l] + sb2;
                vx = vv * x1;
            }
            unsigned short h = f2bf(vx);
            unsigned short lo16 = f2bf(vx - bf2f(h));
            VH(b)[idx] = h;
            VL(b)[idx] = lo16;
        }
    }
    __syncthreads();

    // ---- phase 1: MFMA Toeplitz sweep --------------------------------------
    const int wv = tid >> 6, lane = tid & 63;
    const int row = lane & 15;        // = A row i-block base, = B col n
    const int sseg = lane >> 4;       // k-segment 0..3
    f32x4 acc[2][4] = {};
#pragma unroll
    for (int gi = 0; gi < 2; ++gi) {
        const int g = gi ? (7 - wv) : wv;
        const int tmax = 8 * g + 8;
        int xA = 2031 - row + 8 * sseg;                 // dword idx into w arrays
        int xB = 224 + 256 * g + 16 * row + 8 * sseg;   // bf16 idx into vxa
        for (int t = 0; t < tmax; ++t) {
            int4 avh, avl;
            avh.x = whi[xA];     avh.y = whi[xA + 2];
            avh.z = whi[xA + 4]; avh.w = whi[xA + 6];
            avl.x = wlo[xA];     avl.y = wlo[xA + 2];
            avl.z = wlo[xA + 4]; avl.w = wlo[xA + 6];
            bf16x8 ah = __builtin_bit_cast(bf16x8, avh);
            bf16x8 al = __builtin_bit_cast(bf16x8, avl);
#pragma unroll
            for (int b = 0; b < 4; ++b) {
                bf16x8 bh = *(const bf16x8*)(VH(b) + xB);
                bf16x8 bl = *(const bf16x8*)(VL(b) + xB);
                acc[gi][b] = __builtin_amdgcn_mfma_f32_16x16x32_bf16(ah, bh, acc[gi][b], 0, 0, 0);
                acc[gi][b] = __builtin_amdgcn_mfma_f32_16x16x32_bf16(ah, bl, acc[gi][b], 0, 0, 0);
                acc[gi][b] = __builtin_amdgcn_mfma_f32_16x16x32_bf16(al, bh, acc[gi][b], 0, 0, 0);
            }
            xA -= 32;
            xB -= 32;
        }
    }

    // ---- phase 2: epilogue (two halves of b to keep LDS under 64K) ---------
    const float w0a = sw[d * 3 + 0], w0b = sw[d * 3 + 1], w0c = sw[d * 3 + 2];
    const float sb0 = sb[d];
    const float fb = fbias[d];
#pragma unroll
    for (int half = 0; half < 2; ++half) {
        __syncthreads();   // waves done reading whi/wlo (and prev x0p)
        for (int l = tid; l < 2048; l += 256) {
#pragma unroll
            for (int bb = 0; bb < 2; ++bb) {
                const int b = half * 2 + bb;
                const float* r0 = up_t + ((size_t)(b * 3072) + d) * 2048;
                float a2 = (l >= 2) ? r0[l - 2] : 0.f;
                float a1 = (l >= 1) ? r0[l - 1] : 0.f;
                x0p[bb * 2176 + l + (l >> 4)] = w0a * a2 + w0b * a1 + w0c * r0[l] + sb0;
            }
        }
        __syncthreads();
#pragma unroll
        for (int gi = 0; gi < 2; ++gi) {
            const int g = gi ? (7 - wv) : wv;
            const int lb = 256 * g + 16 * row + 4 * sseg;
#pragma unroll
            for (int bb = 0; bb < 2; ++bb) {
                const int b = half * 2 + bb;
                ushort4 vhq = *(const ushort4*)(VH(b) + 240 + lb);
                ushort4 vlq = *(const ushort4*)(VL(b) + 240 + lb);
                const float* xp = x0p + bb * 2176;
                const int xi = lb + (lb >> 4);
                f32x4 a = acc[gi][b];
                float4 o;
                o.x = (a[0] + (bf2f(vhq.x) + bf2f(vlq.x)) * fb) * xp[xi + 0];
                o.y = (a[1] + (bf2f(vhq.y) + bf2f(vlq.y)) * fb) * xp[xi + 1];
                o.z = (a[2] + (bf2f(vhq.z) + bf2f(vlq.z)) * fb) * xp[xi + 2];
                o.w = (a[3] + (bf2f(vhq.w) + bf2f(vlq.w)) * fb) * xp[xi + 3];
                *(float4*)&yv[((size_t)(b * 1024) + d) * 2048 + lb] = o;
            }
        }
    }
#undef VH
#undef VL
}

extern "C" void kernel_launch(void* const* d_in, const int* in_sizes, int n_in,
                              void* d_out, int out_size, void* d_ws, size_t ws_size,
                              hipStream_t stream) {
    (void)in_sizes; (void)n_in; (void)out_size; (void)ws_size;
    const float* u         = (const float*)d_in[0];
    const float* in_w      = (const float*)d_in[1];
    const float* in_b      = (const float*)d_in[2];
    const float* short_w   = (const float*)d_in[3];
    const float* short_b   = (const float*)d_in[4];
    const float* mlp_w1    = (const float*)d_in[5];
    const float* mlp_b1    = (const float*)d_in[6];
    const float* mlp_w2    = (const float*)d_in[7];
    const float* mlp_b2    = (const float*)d_in[8];
    const float* mlp_w3    = (const float*)d_in[9];
    const float* mlp_b3    = (const float*)d_in[10];
    const float* mlp_wo    = (const float*)d_in[11];
    const float* freq      = (const float*)d_in[12];
    const float* filt_bias = (const float*)d_in[13];
    const float* out_w     = (const float*)d_in[14];
    const float* out_b     = (const float*)d_in[15];
    float* out = (float*)d_out;

    char* ws = (char*)d_ws;
    const size_t MB = 1024 * 1024;
    float*          up_t    = (float*)ws;                       // [0,96M)
    unsigned short* yvt_hi  = (unsigned short*)ws;              // reuse after conv [0,16M)
    unsigned short* yvt_lo  = (unsigned short*)(ws + 16 * MB);  // [16,32M)
    float*          kbuf    = (float*)(ws + 96 * MB);           // [96,104M)
    unsigned short* uhi     = (unsigned short*)(ws + 104 * MB); // [104,120M)
    unsigned short* ulo     = (unsigned short*)(ws + 120 * MB); // [120,136M)
    float*          yvb     = (float*)(ws + 104 * MB);          // reuse after gemm1 [104,136M)
    unsigned short* w1t_hi  = (unsigned short*)(ws + 136 * MB); // [136,142M)
    unsigned short* w1t_lo  = (unsigned short*)(ws + 142 * MB); // [142,148M)
    unsigned short* w2t_hi  = (unsigned short*)(ws + 148 * MB); // [148,150M)
    unsigned short* w2t_lo  = (unsigned short*)(ws + 150 * MB); // [150,152M)

    hipLaunchKernelGGL(split_kernel, dim3(8192), dim3(256), 0, stream,
                       u, uhi, ulo, 8192 * 1024 / 4);
    hipLaunchKernelGGL(tsplit_kernel, dim3(96, 32, 1), dim3(256), 0, stream,
                       in_w, w1t_hi, w1t_lo, 1024, 3072, 0L, 0L);
    hipLaunchKernelGGL(filt_kernel, dim3(2048), dim3(256), 0, stream,
                       mlp_w1, mlp_b1, mlp_w2, mlp_b2, mlp_w3, mlp_b3, mlp_wo, freq, kbuf);
    hipLaunchKernelGGL((gemm_split_kernel<1>), dim3(24, 64), dim3(256), 0, stream,
                       uhi, ulo, w1t_hi, w1t_lo, in_b, up_t);
    hipLaunchKernelGGL(conv_kernel, dim3(1024), dim3(256), 0, stream,
                       up_t, kbuf, short_w, short_b, filt_bias, yvb);
    hipLaunchKernelGGL(tsplit_kernel, dim3(64, 32, 4), dim3(256), 0, stream,
                       yvb, yvt_hi, yvt_lo, 1024, 2048, 1024L * 2048L, 2048L * 1024L);
    hipLaunchKernelGGL(tsplit_kernel, dim3(32, 32, 1), dim3(256), 0, stream,
                       out_w, w2t_hi, w2t_lo, 1024, 1024, 0L, 0L);
    hipLaunchKernelGGL((gemm_split_kernel<0>), dim3(8, 64), dim3(256), 0, stream,
                       yvt_hi, yvt_lo, w2t_hi, w2t_lo, out_b, out);
}

// Round 4
// 205.923 us; speedup vs baseline: 6.4918x; 1.8311x over previous
//
#include <hip/hip_runtime.h>
#include <math.h>

#define M_PIf 3.14159265358979323846f
#define MIND (-3.0701134573253936f)
#define MAXD (-15.350567286626968f)

typedef __attribute__((ext_vector_type(8))) _Float16 f16x8;
typedef __attribute__((ext_vector_type(4))) float f32x4;

#define GLDS(g, l) __builtin_amdgcn_global_load_lds(                         \
    (const __attribute__((address_space(1))) void*)(g),                      \
    (__attribute__((address_space(3))) void*)(l), 16, 0, 0)

__device__ __forceinline__ unsigned short f2h(float x) {
    return __builtin_bit_cast(unsigned short, (_Float16)x);
}
__device__ __forceinline__ float h2f(unsigned short h) {
    return (float)__builtin_bit_cast(_Float16, h);
}

// ---------------------------------------------------------------------------
// split: f32 array -> fp16 array (same layout)
// ---------------------------------------------------------------------------
__global__ __launch_bounds__(256) void split_kernel(
    const float* __restrict__ in, unsigned short* __restrict__ out, int n4)
{
    int i = blockIdx.x * 256 + threadIdx.x;
    if (i >= n4) return;
    float4 v = ((const float4*)in)[i];
    ushort4 h;
    h.x = f2h(v.x); h.y = f2h(v.y); h.z = f2h(v.z); h.w = f2h(v.w);
    ((ushort4*)out)[i] = h;
}

// ---------------------------------------------------------------------------
// transpose + to-fp16: in[R][C] f32 -> out[C][R] fp16 (batched via z)
// ---------------------------------------------------------------------------
__global__ __launch_bounds__(256) void tsplit_kernel(
    const float* __restrict__ in, unsigned short* __restrict__ out,
    int R, int C, long in_zstride, long out_zstride)
{
    __shared__ float t[32][33];
    const float* inz = in + (size_t)blockIdx.z * in_zstride;
    const int r0 = blockIdx.y * 32, c0 = blockIdx.x * 32;
    const int tx = threadIdx.x & 31, ty = threadIdx.x >> 5;
#pragma unroll
    for (int q = 0; q < 4; ++q) {
        int r = ty + q * 8;
        t[r][tx] = inz[(size_t)(r0 + r) * C + c0 + tx];
    }
    __syncthreads();
#pragma unroll
    for (int q = 0; q < 4; ++q) {
        int cc = ty + q * 8;
        size_t o = (size_t)blockIdx.z * out_zstride + (size_t)(c0 + cc) * R + r0 + tx;
        out[o] = f2h(t[tx][cc]);
    }
}

// ---------------------------------------------------------------------------
// fp16 MFMA GEMM: C[M x N] = A[M x 1024] @ B[1024 x N] (+bias on N)
// A row-major fp16 [M][1024]; B TRANSPOSED fp16 [N][1024].
// 128x128 tile, BK=32, 4 waves (each 64x64), 16x16x32 f16 MFMA.
// ---------------------------------------------------------------------------
template <int TRANS_OUT>
__global__ __launch_bounds__(256, 2) void gemm_f16_kernel(
    const unsigned short* __restrict__ A, const unsigned short* __restrict__ B,
    const float* __restrict__ bias, float* __restrict__ outp)
{
    __shared__ char smem[36864];   // staging: [2 buf][2 arr][128 rows][64 B] = 32K
    const int tid = threadIdx.x;
    const int wave = tid >> 6, lane = tid & 63;
    const int n0 = blockIdx.x * 128, m0 = blockIdx.y * 128;
    const int wm = wave >> 1, wn = wave & 1;

    f32x4 acc[4][4] = {};

    const int srow = lane >> 2;          // 0..15 row within 16-row chunk
    const int scol = (lane & 3) * 16;    // byte within 64B row

    auto stage = [&](int buf, int t) {
        const int k0 = t * 32;
        char* base = smem + buf * 16384;
#pragma unroll
        for (int ld = 0; ld < 2; ++ld) {
            const int rchunk = wave * 32 + ld * 16;
            const int r = rchunk + srow;
            GLDS((const char*)(A + (size_t)(m0 + r) * 1024 + k0) + scol,
                 base + 0 * 8192 + rchunk * 64);
            GLDS((const char*)(B + (size_t)(n0 + r) * 1024 + k0) + scol,
                 base + 1 * 8192 + rchunk * 64);
        }
    };

    stage(0, 0);
    asm volatile("s_waitcnt vmcnt(0)");
    __syncthreads();
    int cur = 0;
    const int rr = lane & 15, gg = (lane >> 4) * 16;
    for (int t = 0; t < 32; ++t) {
        if (t < 31) stage(cur ^ 1, t + 1);
        const char* b = smem + cur * 16384;
        f16x8 ah[4], bh[4];
#pragma unroll
        for (int i = 0; i < 4; ++i) {
            ah[i] = *(const f16x8*)(b + 0 * 8192 + (wm * 64 + i * 16 + rr) * 64 + gg);
            bh[i] = *(const f16x8*)(b + 1 * 8192 + (wn * 64 + i * 16 + rr) * 64 + gg);
        }
#pragma unroll
        for (int i = 0; i < 4; ++i)
#pragma unroll
            for (int j = 0; j < 4; ++j)
                acc[i][j] = __builtin_amdgcn_mfma_f32_16x16x32_f16(ah[i], bh[j], acc[i][j], 0, 0, 0);
        __syncthreads();
        cur ^= 1;
    }

    const int c = lane & 15, g4 = lane >> 4;
    if (TRANS_OUT) {
        // transpose 64x64 wave tile through LDS, write up_t[b][e][l] coalesced
        float* scr = (float*)smem + wave * (32 * 68);
        const int bidx = m0 >> 11;
        const int lbase = (m0 & 2047) + wm * 64;
#pragma unroll
        for (int p = 0; p < 2; ++p) {
#pragma unroll
            for (int j = 0; j < 2; ++j) {
                const int jj = p * 2 + j;
                const float bv = bias[n0 + wn * 64 + jj * 16 + c];
#pragma unroll
                for (int i = 0; i < 4; ++i)
#pragma unroll
                    for (int r = 0; r < 4; ++r)
                        scr[(j * 16 + c) * 68 + i * 16 + g4 * 4 + r] = acc[i][jj][r] + bv;
            }
#pragma unroll
            for (int it = 0; it < 8; ++it) {
                const int row = it * 4 + g4;
                float4 v = *(const float4*)&scr[row * 68 + c * 4];
                const int e = n0 + wn * 64 + p * 32 + row;
                *(float4*)&outp[((size_t)bidx * 3072 + e) * 2048 + lbase + c * 4] = v;
            }
            __syncthreads();
        }
    } else {
#pragma unroll
        for (int j = 0; j < 4; ++j) {
            const int col = n0 + wn * 64 + j * 16 + c;
            const float bv = bias[col];
#pragma unroll
            for (int i = 0; i < 4; ++i) {
                const int row = m0 + wm * 64 + i * 16 + g4 * 4;
#pragma unroll
                for (int r = 0; r < 4; ++r)
                    outp[(size_t)(row + r) * 1024 + col] = acc[i][j][r] + bv;
            }
        }
    }
}

// ---------------------------------------------------------------------------
// Filter MLP: k[d, l]. 256 blocks x 8 positions; wo loop-hoisted so each
// block reads wo once (64 MB total L2 traffic instead of 512 MB).
// ---------------------------------------------------------------------------
__global__ __launch_bounds__(256) void filt_kernel(
    const float* __restrict__ w1, const float* __restrict__ b1,
    const float* __restrict__ w2, const float* __restrict__ b2,
    const float* __restrict__ w3, const float* __restrict__ b3,
    const float* __restrict__ wo, const float* __restrict__ freq,
    float* __restrict__ kbuf)
{
    __shared__ float ha[8][65], hb[8][65];
    const int l0 = blockIdx.x * 8;
    const int tid = threadIdx.x;
    const int uu = tid & 63, lq = tid >> 6;   // lq = 0..3
#pragma unroll
    for (int p = 0; p < 2; ++p) {
        int ll = lq + p * 4;
        int l = l0 + ll;
        float t = (float)l * (1.0f / 2047.0f);
        float ang = 1e-4f * (2.0f * M_PIf) * ((float)l / 2048.0f);
        float pre = t * w1[uu] + cosf(ang) * w1[64 + uu] - sinf(ang) * w1[128 + uu] + b1[uu];
        ha[ll][uu] = sinf(freq[uu] * pre);
    }
    __syncthreads();
#pragma unroll
    for (int p = 0; p < 2; ++p) {
        int ll = lq + p * 4;
        float s = b2[uu];
#pragma unroll
        for (int i = 0; i < 64; ++i) s += ha[ll][i] * w2[i * 64 + uu];
        hb[ll][uu] = sinf(freq[uu] * s);
    }
    __syncthreads();
#pragma unroll
    for (int p = 0; p < 2; ++p) {
        int ll = lq + p * 4;
        float s = b3[uu];
#pragma unroll
        for (int i = 0; i < 64; ++i) s += hb[ll][i] * w3[i * 64 + uu];
        ha[ll][uu] = sinf(freq[uu] * s);
    }
    __syncthreads();

    float acc[4][8] = {};
    for (int i = 0; i < 64; ++i) {
        float wv[4];
#pragma unroll
        for (int q = 0; q < 4; ++q) wv[q] = wo[i * 1024 + tid + 256 * q];
#pragma unroll
        for (int l = 0; l < 8; ++l) {
            float hv = ha[l][i];
#pragma unroll
            for (int q = 0; q < 4; ++q) acc[q][l] += hv * wv[q];
        }
    }
    const float span = (MAXD - MIND) * (1.0f / 1023.0f);
#pragma unroll
    for (int q = 0; q < 4; ++q) {
        int dd = tid + 256 * q;
        float ad = fabsf(MIND + span * (float)dd);
#pragma unroll
        for (int l = 0; l < 8; ++l) {
            float t = (float)(l0 + l) * (1.0f / 2047.0f);
            kbuf[(size_t)dd * 2048 + l0 + l] = acc[q][l] * expf(-t * ad);
        }
    }
}

// ---------------------------------------------------------------------------
// MFMA Toeplitz causal conv (fp16), fused with depthwise conv3 gating.
// One block per d, 4 waves, all 4 batches.
// ---------------------------------------------------------------------------
__global__ __launch_bounds__(256, 2) void conv_kernel(
    const float* __restrict__ up_t, const float* __restrict__ kbuf,
    const float* __restrict__ sw, const float* __restrict__ sb,
    const float* __restrict__ fbias, float* __restrict__ yv)
{
    __shared__ char smem[35840];
    // vxa: per b fp16[2304] @ b*4608                      (18432 B)
    // w:   int[2064] @ 18432 (8256 B)        (phases 0-1)
    // x0p: f32[2][2176] @ 18432 (17408 B)    (phase 2, overlays w)
#define VH(b) ((unsigned short*)(smem + (b) * 4608))
    int* wpk = (int*)(smem + 18432);
    float* x0p = (float*)(smem + 18432);

    const int d = blockIdx.x;
    const int tid = threadIdx.x;

    // ---- phase 0a: reversed-k pair-dword array -----------------------------
    const float* kr = kbuf + (size_t)d * 2048;
    for (int x = tid; x < 2064; x += 256) {
        int k1 = 2047 - x;
        float f1 = (k1 >= 0) ? kr[k1] : 0.f;
        float f2 = (k1 >= 1) ? kr[k1 - 1] : 0.f;
        wpk[x] = (int)((unsigned)f2h(f1) | ((unsigned)f2h(f2) << 16));
    }
    // ---- phase 0b: vx = conv3(x1)*conv3(v), fp16, pad P=240 ----------------
    const float w1a = sw[(1024 + d) * 3 + 0], w1b = sw[(1024 + d) * 3 + 1], w1c = sw[(1024 + d) * 3 + 2];
    const float w2a = sw[(2048 + d) * 3 + 0], w2b = sw[(2048 + d) * 3 + 1], w2c = sw[(2048 + d) * 3 + 2];
    const float sb1 = sb[1024 + d], sb2 = sb[2048 + d];
    for (int idx = tid; idx < 2304; idx += 256) {
        int l = idx - 240;
#pragma unroll
        for (int b = 0; b < 4; ++b) {
            float vx = 0.f;
            if (l >= 0 && l < 2048) {
                const float* rx1 = up_t + ((size_t)(b * 3072) + 1024 + d) * 2048;
                const float* rv  = up_t + ((size_t)(b * 3072) + 2048 + d) * 2048;
                float a2 = (l >= 2) ? rx1[l - 2] : 0.f;
                float a1 = (l >= 1) ? rx1[l - 1] : 0.f;
                float x1 = w1a * a2 + w1b * a1 + w1c * rx1[l] + sb1;
                float c2 = (l >= 2) ? rv[l - 2] : 0.f;
                float c1 = (l >= 1) ? rv[l - 1] : 0.f;
                float vv = w2a * c2 + w2b * c1 + w2c * rv[l] + sb2;
                vx = vv * x1;
            }
            VH(b)[idx] = f2h(vx);
        }
    }
    __syncthreads();

    // ---- phase 1: MFMA Toeplitz sweep --------------------------------------
    const int wv = tid >> 6, lane = tid & 63;
    const int row = lane & 15;
    const int sseg = lane >> 4;
    f32x4 acc[2][4] = {};
#pragma unroll
    for (int gi = 0; gi < 2; ++gi) {
        const int g = gi ? (7 - wv) : wv;
        const int tmax = 8 * g + 8;
        int xA = 2031 - row + 8 * sseg;
        int xB = 224 + 256 * g + 16 * row + 8 * sseg;
        for (int t = 0; t < tmax; ++t) {
            int4 avh;
            avh.x = wpk[xA];     avh.y = wpk[xA + 2];
            avh.z = wpk[xA + 4]; avh.w = wpk[xA + 6];
            f16x8 ah = __builtin_bit_cast(f16x8, avh);
#pragma unroll
            for (int b = 0; b < 4; ++b) {
                f16x8 bh = *(const f16x8*)(VH(b) + xB);
                acc[gi][b] = __builtin_amdgcn_mfma_f32_16x16x32_f16(ah, bh, acc[gi][b], 0, 0, 0);
            }
            xA -= 32;
            xB -= 32;
        }
    }

    // ---- phase 2: epilogue (two halves; x0p overlays wpk) ------------------
    const float w0a = sw[d * 3 + 0], w0b = sw[d * 3 + 1], w0c = sw[d * 3 + 2];
    const float sb0 = sb[d];
    const float fb = fbias[d];
#pragma unroll
    for (int half = 0; half < 2; ++half) {
        __syncthreads();
        for (int l = tid; l < 2048; l += 256) {
#pragma unroll
            for (int bb = 0; bb < 2; ++bb) {
                const int b = half * 2 + bb;
                const float* r0 = up_t + ((size_t)(b * 3072) + d) * 2048;
                float a2 = (l >= 2) ? r0[l - 2] : 0.f;
                float a1 = (l >= 1) ? r0[l - 1] : 0.f;
                x0p[bb * 2176 + l + (l >> 4)] = w0a * a2 + w0b * a1 + w0c * r0[l] + sb0;
            }
        }
        __syncthreads();
#pragma unroll
        for (int gi = 0; gi < 2; ++gi) {
            const int g = gi ? (7 - wv) : wv;
            const int lb = 256 * g + 16 * row + 4 * sseg;
#pragma unroll
            for (int bb = 0; bb < 2; ++bb) {
                const int b = half * 2 + bb;
                ushort4 vhq = *(const ushort4*)(VH(b) + 240 + lb);
                const float* xp = x0p + bb * 2176;
                const int xi = lb + (lb >> 4);
                f32x4 a = acc[gi][b];
                float4 o;
                o.x = (a[0] + h2f(vhq.x) * fb) * xp[xi + 0];
                o.y = (a[1] + h2f(vhq.y) * fb) * xp[xi + 1];
                o.z = (a[2] + h2f(vhq.z) * fb) * xp[xi + 2];
                o.w = (a[3] + h2f(vhq.w) * fb) * xp[xi + 3];
                *(float4*)&yv[((size_t)(b * 1024) + d) * 2048 + lb] = o;
            }
        }
    }
#undef VH
}

extern "C" void kernel_launch(void* const* d_in, const int* in_sizes, int n_in,
                              void* d_out, int out_size, void* d_ws, size_t ws_size,
                              hipStream_t stream) {
    (void)in_sizes; (void)n_in; (void)out_size; (void)ws_size;
    const float* u         = (const float*)d_in[0];
    const float* in_w      = (const float*)d_in[1];
    const float* in_b      = (const float*)d_in[2];
    const float* short_w   = (const float*)d_in[3];
    const float* short_b   = (const float*)d_in[4];
    const float* mlp_w1    = (const float*)d_in[5];
    const float* mlp_b1    = (const float*)d_in[6];
    const float* mlp_w2    = (const float*)d_in[7];
    const float* mlp_b2    = (const float*)d_in[8];
    const float* mlp_w3    = (const float*)d_in[9];
    const float* mlp_b3    = (const float*)d_in[10];
    const float* mlp_wo    = (const float*)d_in[11];
    const float* freq      = (const float*)d_in[12];
    const float* filt_bias = (const float*)d_in[13];
    const float* out_w     = (const float*)d_in[14];
    const float* out_b     = (const float*)d_in[15];
    float* out = (float*)d_out;

    char* ws = (char*)d_ws;
    const size_t MB = 1024 * 1024;
    float*          up_t  = (float*)ws;                       // [0,96M)
    unsigned short* yvt   = (unsigned short*)ws;              // reuse after conv [0,16M)
    float*          kbuf  = (float*)(ws + 96 * MB);           // [96,104M)
    unsigned short* uh    = (unsigned short*)(ws + 104 * MB); // [104,120M)
    unsigned short* w1t   = (unsigned short*)(ws + 120 * MB); // [120,126M)
    float*          yvb   = (float*)(ws + 104 * MB);          // reuse after gemm1 [104,136M)
    unsigned short* w2t   = (unsigned short*)(ws + 136 * MB); // [136,138M)

    hipLaunchKernelGGL(split_kernel, dim3(8192), dim3(256), 0, stream,
                       u, uh, 8192 * 1024 / 4);
    hipLaunchKernelGGL(tsplit_kernel, dim3(96, 32, 1), dim3(256), 0, stream,
                       in_w, w1t, 1024, 3072, 0L, 0L);
    hipLaunchKernelGGL(filt_kernel, dim3(256), dim3(256), 0, stream,
                       mlp_w1, mlp_b1, mlp_w2, mlp_b2, mlp_w3, mlp_b3, mlp_wo, freq, kbuf);
    hipLaunchKernelGGL((gemm_f16_kernel<1>), dim3(24, 64), dim3(256), 0, stream,
                       uh, w1t, in_b, up_t);
    hipLaunchKernelGGL(conv_kernel, dim3(1024), dim3(256), 0, stream,
                       up_t, kbuf, short_w, short_b, filt_bias, yvb);
    hipLaunchKernelGGL(tsplit_kernel, dim3(64, 32, 4), dim3(256), 0, stream,
                       yvb, yvt, 1024, 2048, 1024L * 2048L, 2048L * 1024L);
    hipLaunchKernelGGL(tsplit_kernel, dim3(32, 32, 1), dim3(256), 0, stream,
                       out_w, w2t, 1024, 1024, 0L, 0L);
    hipLaunchKernelGGL((gemm_f16_kernel<0>), dim3(8, 64), dim3(256), 0, stream,
                       yvt, w2t, out_b, out);
}